// Round 22
// baseline (50.379 us; speedup 1.0000x reference)
//
#include <hip/hip_runtime.h>
#include <math.h>

// QNN. Storage basis = post-P1. All 54 RX gates are (c I - i s X_D) with
// XOR-masks D; they ALL COMMUTE. Conjugated masks (HW-verified R16/R17/R20):
// L1: e_p; L2: pinv(e_q); L3: pinv^2(e_q).
// X1 span {0..8,15,16,17} (33 gates, init-fused group + 10 triple-rounds,
// Gray-orbit ratio-walk init; 64 x 512). X2 span {7..17} (21 gates, 7
// triple-rounds, bf16 |amp|^2 + P^3 scatter; 128 x 256). k_mm: MFMA,
// CH=64/CPB=4/1024 blocks (4 blocks/CU, 3/4 prefetch coverage). 4 nodes.

#define DIM (1 << 18)
#define NW 18
#define CH 64
#define CPB 4
#define NMM 1024
#define PAD16(i) ((i) + ((i) >> 4))

typedef short short8 __attribute__((ext_vector_type(8)));
typedef float f32x4  __attribute__((ext_vector_type(4)));

__device__ __forceinline__ unsigned perm18(unsigned i) {
    unsigned s = i;
    s ^= s >> 1; s ^= s >> 2; s ^= s >> 4; s ^= s >> 8; s ^= s >> 16;
    unsigned out = s & 0x1FFFFu;
    out |= ((s ^ (i >> 17)) & 1u) << 17;
    return out;
}
__device__ __forceinline__ unsigned pinv18(unsigned b) {
    unsigned t = b & 0x1FFFFu;
    unsigned u = (t ^ (t >> 1)) & 0xFFFFu;
    unsigned i17 = ((b >> 17) ^ t) & 1u;
    unsigned i16 = ((t >> 16) ^ i17) & 1u;
    return u | (i16 << 16) | (i17 << 17);
}
__device__ __forceinline__ void bfly(float2& a0, float2& a1, float c, float s) {
    float2 n0 = make_float2(c * a0.x + s * a1.y, c * a0.y - s * a1.x);
    float2 n1 = make_float2(c * a1.x + s * a0.y, c * a1.y - s * a0.x);
    a0 = n0; a1 = n1;
}
__device__ __forceinline__ short f2bf(float x) {
    unsigned u = __float_as_uint(x);
    return (short)((u + 0x7FFFu + ((u >> 16) & 1u)) >> 16);
}

// masks/angles (HW-verified). X1 local bits: r0..8=g0..8, r9..11=g15..17.
constexpr unsigned cX1M[33] = {
    0x001,0x002,0x004,0x008,0x010,0x020,0x040,0x080,0x100,0x200,0x400,0x800,
    0xC01,0xC03,0xC06,0xC0C,0xC18,0xC30,0xC60,0xCC0,0xD80,0xA00,0xC00,
    0xA01,0x602,0x605,0x60A,0x614,0x628,0x650,0x6A0,0x740,0x600};
constexpr unsigned char cX1A[33] = {
    35,34,33,32,31,30,29,28,27,20,19,18,
    53,52,51,50,49,48,47,46,45,37,36,
    71,70,69,68,67,66,65,64,63,54};
// X2 local bits: r = g - 7.
constexpr unsigned cX2M[21] = {
    0x004,0x008,0x010,0x020,0x040,0x080,
    0x606,0x60C,0x618,0x630,0x660,0x6C0,0x780,
    0x305,0x30A,0x314,0x328,0x350,0x3A0,0x240,0x180};
constexpr unsigned char cX2A[21] = {
    26,25,24,23,22,21,
    44,43,42,41,40,39,38,
    62,61,60,59,58,57,56,55};

constexpr int ctzc(unsigned x) { int n = 0; while (!(x & 1u)) { x >>= 1; ++n; } return n; }

// apply one gate (pairing coordinate C in orbit space) to 8-elem register set
template<int C>
__device__ __forceinline__ void applyG(float2* E, float2 g) {
    constexpr int L = C & (-C);
#pragma unroll
    for (int v = 0; v < 8; ++v)
        if (!(v & L)) bfly(E[v], E[v ^ C], g.x, g.y);
}

// three commuting gates per round over an 8-element orbit; all compile-time.
template<unsigned M1, unsigned M2, unsigned M3, int T, int NT>
__device__ __forceinline__ void triR(float2* t, float2 g1, float2 g2, float2 g3) {
    constexpr unsigned z1 = M1 & (0u - M1);
    constexpr unsigned B2a = (M2 & z1) ? (M2 ^ M1) : M2;
    constexpr unsigned z2 = B2a & (0u - B2a);
    constexpr unsigned B1a = (M1 & z2) ? (M1 ^ B2a) : M1;
    constexpr unsigned B3a = (M3 & z1) ? (M3 ^ B1a) : M3;
    constexpr unsigned B3b = (B3a & z2) ? (B3a ^ B2a) : B3a;
    constexpr unsigned z3 = B3b & (0u - B3b);
    constexpr unsigned B1 = (B1a & z3) ? (B1a ^ B3b) : B1a;
    constexpr unsigned B2 = (B2a & z3) ? (B2a ^ B3b) : B2a;
    constexpr unsigned B3 = B3b;
    constexpr int c1 = ((M1 & z1) ? 1 : 0) | ((M1 & z2) ? 2 : 0) | ((M1 & z3) ? 4 : 0);
    constexpr int c2 = ((M2 & z1) ? 1 : 0) | ((M2 & z2) ? 2 : 0) | ((M2 & z3) ? 4 : 0);
    constexpr int c3 = ((M3 & z1) ? 1 : 0) | ((M3 & z2) ? 2 : 0) | ((M3 & z3) ? 4 : 0);
    constexpr int q1 = ctzc(z1), q2 = ctzc(z2), q3 = ctzc(z3);
    constexpr int pa = (q1 < q2 ? (q1 < q3 ? q1 : q3) : (q2 < q3 ? q2 : q3));
    constexpr int pc = (q1 > q2 ? (q1 > q3 ? q1 : q3) : (q2 > q3 ? q2 : q3));
    constexpr int pb = q1 + q2 + q3 - pa - pc;
#pragma unroll
    for (int it = 0; it < (T / 8) / NT; ++it) {
        unsigned k = (unsigned)threadIdx.x + (unsigned)(it * NT);
        unsigned i = ((k >> pa) << (pa + 1)) | (k & ((1u << pa) - 1u));
        i = ((i >> pb) << (pb + 1)) | (i & ((1u << pb) - 1u));
        i = ((i >> pc) << (pc + 1)) | (i & ((1u << pc) - 1u));
        int idx[8];
        float2 E[8];
#pragma unroll
        for (int v = 0; v < 8; ++v) {
            unsigned e = i ^ ((v & 1) ? B1 : 0u) ^ ((v & 2) ? B2 : 0u) ^ ((v & 4) ? B3 : 0u);
            idx[v] = PAD16((int)e);
            E[v] = t[idx[v]];
        }
        applyG<c1>(E, g1);
        applyG<c2>(E, g2);
        applyG<c3>(E, g3);
#pragma unroll
        for (int v = 0; v < 8; ++v) t[idx[v]] = E[v];
    }
}

// ---- X1: analytic init (Gray-orbit ratio walk) + 33 gates; 64 x 512 -------
__global__ __launch_bounds__(512) void kX1(float2* __restrict__ out, const float* __restrict__ qw) {
    __shared__ float2 t[4352];
    __shared__ float2 g[33];
    int tid = threadIdx.x;
    if (tid < 33) { float th = qw[cX1A[tid]] * 0.5f; g[tid] = make_float2(cosf(th), sinf(th)); }
    float c0[NW], s0[NW];
#pragma unroll
    for (int w = 0; w < NW; ++w) { float th = qw[w] * 0.5f; c0[w] = cosf(th); s0[w] = sinf(th); }
    unsigned blk = blockIdx.x;                 // global bits 9..14
    unsigned l0 = 8u * (unsigned)tid;
    unsigned b0 = (l0 & 511u) | (blk << 9) | ((l0 >> 9) << 15);
    unsigned i0 = pinv18(b0);
    float m0 = 1.f;
#pragma unroll
    for (int p = 0; p < 18; ++p) m0 *= ((i0 >> p) & 1u) ? s0[17 - p] : c0[17 - p];
    float rA0 = s0[17] / c0[17], rB0 = c0[17] / s0[17];
    float rA1 = s0[16] / c0[16], rB1 = c0[16] / s0[16];
    float rA2 = s0[15] / c0[15], rB2 = c0[15] / s0[15];
    float rA16 = s0[1] / c0[1], rB16 = c0[1] / s0[1];
    float rA17 = s0[0] / c0[0], rB17 = c0[0] / s0[0];
    float2 E[8];
    {
        unsigned i = i0;
        float m = m0;
        auto quad = [&](unsigned ii, float mm) {
            int k4 = __popc(ii) & 3;
            if      (k4 == 0) return make_float2( mm, 0.f);
            else if (k4 == 1) return make_float2(0.f, -mm);
            else if (k4 == 2) return make_float2(-mm, 0.f);
            else              return make_float2(0.f,  mm);
        };
        auto togQ1 = [&]() {    // bits {0,16,17}
            i ^= 0x30001u;
            m *= ((i) & 1u) ? rA0 : rB0;
            m *= ((i >> 16) & 1u) ? rA16 : rB16;
            m *= ((i >> 17) & 1u) ? rA17 : rB17;
        };
        auto togQ2 = [&]() {    // bits {0,1}
            i ^= 0x3u;
            m *= ((i) & 1u) ? rA0 : rB0;
            m *= ((i >> 1) & 1u) ? rA1 : rB1;
        };
        auto togQ4 = [&]() {    // bits {1,2}
            i ^= 0x6u;
            m *= ((i >> 1) & 1u) ? rA1 : rB1;
            m *= ((i >> 2) & 1u) ? rA2 : rB2;
        };
        E[0] = quad(i, m);
        togQ1(); E[1] = quad(i, m);
        togQ2(); E[3] = quad(i, m);
        togQ1(); E[2] = quad(i, m);
        togQ4(); E[6] = quad(i, m);
        togQ1(); E[7] = quad(i, m);
        togQ2(); E[5] = quad(i, m);
        togQ1(); E[4] = quad(i, m);
    }
    __syncthreads();                           // g ready
    applyG<1>(E, g[0]);
    applyG<2>(E, g[1]);
    applyG<4>(E, g[2]);
#pragma unroll
    for (int v = 0; v < 8; ++v) t[PAD16(8 * tid + v)] = E[v];
    __syncthreads();
#define TX1(a) triR<cX1M[a], cX1M[(a)+1], cX1M[(a)+2], 4096, 512>(t, g[a], g[(a)+1], g[(a)+2]); __syncthreads();
    TX1(3) TX1(6) TX1(9) TX1(12) TX1(15) TX1(18) TX1(21) TX1(24) TX1(27) TX1(30)
#undef TX1
#pragma unroll
    for (int r = 0; r < 8; ++r) {
        int l = tid + 512 * r;
        unsigned b = ((unsigned)l & 511u) | (blk << 9) | (((unsigned)l >> 9) << 15);
        out[b] = t[PAD16(l)];
    }
}

// ---- X2: 21 gates on span {7..17} + bf16 |amp|^2 + P^3 scatter; 128 x 256 --
__global__ __launch_bounds__(256) void kX2(const float2* __restrict__ in,
                                           unsigned short* __restrict__ probs,
                                           const float* __restrict__ qw) {
    __shared__ float2 t[2176];
    __shared__ float2 g[21];
    int tid = threadIdx.x;
    if (tid < 21) { float th = qw[cX2A[tid]] * 0.5f; g[tid] = make_float2(cosf(th), sinf(th)); }
    unsigned blk = blockIdx.x;                 // global bits 0..6
#pragma unroll
    for (int r = 0; r < 8; ++r) {
        int l = tid + 256 * r;
        t[PAD16(l)] = in[blk | ((unsigned)l << 7)];
    }
    __syncthreads();
#define TX2(a) triR<cX2M[a], cX2M[(a)+1], cX2M[(a)+2], 2048, 256>(t, g[a], g[(a)+1], g[(a)+2]); __syncthreads();
    TX2(0) TX2(3) TX2(6) TX2(9) TX2(12) TX2(15) TX2(18)
#undef TX2
#pragma unroll
    for (int r = 0; r < 8; ++r) {
        int l = tid + 256 * r;
        unsigned b = blk | ((unsigned)l << 7);
        unsigned pb = perm18(perm18(perm18(b)));
        float2 a = t[PAD16(l)];
        probs[pb] = (unsigned short)f2bf(a.x * a.x + a.y * a.y);
    }
}

// ---- k_mm: MFMA logits partials; bf16 p0; CH=64, 1024 blocks x 4 chunks ----
// Staging: W 64x64 fp32 -> bf16 (thread: rows wrow+16t, float4 col wcol);
// p0 translated (thread: rows prow+4t at pcol). Pitch 72 ushorts (144 B).
__global__ __launch_bounds__(256) void k_mm(const unsigned short* __restrict__ p0,
                                            const float* __restrict__ W,
                                            float* __restrict__ partial) {
    __shared__ short Wl[64][72];
    __shared__ short Pl[16][72];
    __shared__ unsigned Tsh[16];
    int tid = threadIdx.x;
    if (tid < 16) {
        unsigned v = (unsigned)tid;
#pragma unroll
        for (int r = 0; r < 4; ++r) v = perm18(v);
        Tsh[tid] = v;
    }
    __syncthreads();

    unsigned d00 = (unsigned)blockIdx.x * (CH * CPB);
    int wrow = tid >> 4;                   // 0..15
    int wcol = (tid & 15) * 4;             // float4 col 0..60
    int prow = tid >> 6;                   // 0..3
    int pcol = tid & 63;
    unsigned Tp[4];
#pragma unroll
    for (int t = 0; t < 4; ++t) Tp[t] = Tsh[prow + 4 * t];

    int lane = tid & 63, wv = tid >> 6;
    int arow = lane & 15, kg = (lane >> 4) * 8;
    f32x4 acc = {0.f, 0.f, 0.f, 0.f};
    float4 wr[4];
    unsigned short pr[4];

#pragma unroll
    for (int t = 0; t < 4; ++t)
        wr[t] = *(const float4*)&W[(size_t)(wrow + 16 * t) * DIM + d00 + wcol];
#pragma unroll
    for (int t = 0; t < 4; ++t)
        pr[t] = p0[(d00 ^ (Tp[t] & ~63u)) + pcol];
#pragma unroll
    for (int t = 0; t < 4; ++t) {
        short4 b = make_short4(f2bf(wr[t].x), f2bf(wr[t].y), f2bf(wr[t].z), f2bf(wr[t].w));
        *(short4*)&Wl[wrow + 16 * t][wcol] = b;
    }
#pragma unroll
    for (int t = 0; t < 4; ++t)
        Pl[prow + 4 * t][pcol ^ (Tp[t] & 63u)] = (short)pr[t];
    __syncthreads();

    for (int cc = 0; cc < CPB; ++cc) {
        if (cc + 1 < CPB) {
            unsigned d1 = d00 + (unsigned)(cc + 1) * CH;
#pragma unroll
            for (int t = 0; t < 4; ++t)
                wr[t] = *(const float4*)&W[(size_t)(wrow + 16 * t) * DIM + d1 + wcol];
#pragma unroll
            for (int t = 0; t < 4; ++t)
                pr[t] = p0[(d1 ^ (Tp[t] & ~63u)) + pcol];
        }
#pragma unroll
        for (int kk = 0; kk < 2; ++kk) {
            short8 a = *(const short8*)&Pl[arow][kk * 32 + kg];
            short8 b = *(const short8*)&Wl[16 * wv + arow][kk * 32 + kg];
            acc = __builtin_amdgcn_mfma_f32_16x16x32_bf16(a, b, acc, 0, 0, 0);
        }
        __syncthreads();
        if (cc + 1 < CPB) {
#pragma unroll
            for (int t = 0; t < 4; ++t) {
                short4 b = make_short4(f2bf(wr[t].x), f2bf(wr[t].y), f2bf(wr[t].z), f2bf(wr[t].w));
                *(short4*)&Wl[wrow + 16 * t][wcol] = b;
            }
#pragma unroll
            for (int t = 0; t < 4; ++t)
                Pl[prow + 4 * t][pcol ^ (Tp[t] & 63u)] = (short)pr[t];
            __syncthreads();
        }
    }

    float* dst = partial + (size_t)blockIdx.x * 1024;
#pragma unroll
    for (int r = 0; r < 4; ++r) {
        int jrow = (lane >> 4) * 4 + r;
        dst[jrow * 64 + 16 * wv + (lane & 15)] = acc[r];
    }
}

// ---- finalize: reduce partials -> logits; lookup + sigmoid -----------------
__global__ __launch_bounds__(256) void k_finalize(const float* __restrict__ partial,
                                                  const float* __restrict__ bias,
                                                  const int* __restrict__ x,
                                                  float* __restrict__ out) {
    int b = blockIdx.x;
    int tid = threadIdx.x;
    int ji = tid & 15, ci = tid >> 4;
    int jo = b * 16 + ji;
    float sum = 0.f;
#pragma unroll 8
    for (int c = ci; c < NMM; c += 16)
        sum += partial[(size_t)c * 1024 + jo];
    __shared__ float red[16][17];
    __shared__ float lg[16];
    __shared__ int sidx[32];
    red[ci][ji] = sum;
    if (tid < 32) {
        const int* xb = x + (size_t)tid * (16384 * 4);
        sidx[tid] = 8 * xb[0] + 4 * xb[1] + 2 * xb[2] + xb[3];
    }
    __syncthreads();
    if (ci == 0) {
        float s = 0.f;
#pragma unroll
        for (int k = 0; k < 16; ++k) s += red[k][ji];
        lg[ji] = s + bias[jo & 63];
    }
    __syncthreads();
    int myidx = b >> 2, o0 = (b & 3) * 16;
#pragma unroll
    for (int r = 0; r < 2; ++r) {
        int slot = tid + 256 * r;
        int bb = slot >> 4, k = slot & 15;
        if (sidx[bb] == myidx) {
            float z = lg[k];
            out[bb * 64 + o0 + k] = 1.f / (1.f + expf(-z));
        }
    }
}

extern "C" void kernel_launch(void* const* d_in, const int* in_sizes, int n_in,
                              void* d_out, int out_size, void* d_ws, size_t ws_size,
                              hipStream_t stream) {
    const int*   x    = (const int*)d_in[0];
    const float* qw   = (const float*)d_in[1];
    const float* W    = (const float*)d_in[2];
    const float* bias = (const float*)d_in[3];
    float* out = (float*)d_out;

    char* ws = (char*)d_ws;
    float2*         buf0    = (float2*)(ws + (1ull << 20));         // 2 MB
    unsigned short* probs   = (unsigned short*)(ws + (8ull << 20)); // 0.5 MB
    float*          partial = (float*)(ws + (16ull << 20));         // 4 MB

    kX1<<<64, 512, 0, stream>>>(buf0, qw);
    kX2<<<128, 256, 0, stream>>>(buf0, probs, qw);
    k_mm<<<NMM, 256, 0, stream>>>(probs, W, partial);
    k_finalize<<<64, 256, 0, stream>>>(partial, bias, x, out);
}

// Round 23
// 46.741 us; speedup vs baseline: 1.0778x; 1.0778x over previous
//
#include <hip/hip_runtime.h>
#include <math.h>

// QNN. Storage basis = post-P1. All 54 RX gates are (c I - i s X_D) with
// XOR-masks D; they ALL COMMUTE. Conjugated masks (HW-verified R16/R17/R20):
// L1: e_p; L2: pinv(e_q); L3: pinv^2(e_q).
// Two passes: X1 span {0..8,15,16,17} (33 gates = init-fused group + 10
// triple-rounds; 64 blk x 512 thr; analytic init via Gray-orbit ratio walk),
// X2 span {7..17} (21 gates = 7 triple-rounds; 128 x 256; emits bf16 probs
// + P^3 scatter). Then k_mm (MFMA, bf16 p0, CPB=4/512) + k_finalize. 4 nodes.
// R21 config — best measured (46.8 us); R18/R19/R22 perturbations all regressed.

#define DIM (1 << 18)
#define NW 18
#define CH 128
#define CPB 4
#define NMM 512
#define PAD16(i) ((i) + ((i) >> 4))

typedef short short8 __attribute__((ext_vector_type(8)));
typedef float f32x4  __attribute__((ext_vector_type(4)));

__device__ __forceinline__ unsigned perm18(unsigned i) {
    unsigned s = i;
    s ^= s >> 1; s ^= s >> 2; s ^= s >> 4; s ^= s >> 8; s ^= s >> 16;
    unsigned out = s & 0x1FFFFu;
    out |= ((s ^ (i >> 17)) & 1u) << 17;
    return out;
}
__device__ __forceinline__ unsigned pinv18(unsigned b) {
    unsigned t = b & 0x1FFFFu;
    unsigned u = (t ^ (t >> 1)) & 0xFFFFu;
    unsigned i17 = ((b >> 17) ^ t) & 1u;
    unsigned i16 = ((t >> 16) ^ i17) & 1u;
    return u | (i16 << 16) | (i17 << 17);
}
__device__ __forceinline__ void bfly(float2& a0, float2& a1, float c, float s) {
    float2 n0 = make_float2(c * a0.x + s * a1.y, c * a0.y - s * a1.x);
    float2 n1 = make_float2(c * a1.x + s * a0.y, c * a1.y - s * a0.x);
    a0 = n0; a1 = n1;
}
__device__ __forceinline__ short f2bf(float x) {
    unsigned u = __float_as_uint(x);
    return (short)((u + 0x7FFFu + ((u >> 16) & 1u)) >> 16);
}

// masks/angles (HW-verified). X1 local bits: r0..8=g0..8, r9..11=g15..17.
constexpr unsigned cX1M[33] = {
    0x001,0x002,0x004,0x008,0x010,0x020,0x040,0x080,0x100,0x200,0x400,0x800,
    0xC01,0xC03,0xC06,0xC0C,0xC18,0xC30,0xC60,0xCC0,0xD80,0xA00,0xC00,
    0xA01,0x602,0x605,0x60A,0x614,0x628,0x650,0x6A0,0x740,0x600};
constexpr unsigned char cX1A[33] = {
    35,34,33,32,31,30,29,28,27,20,19,18,
    53,52,51,50,49,48,47,46,45,37,36,
    71,70,69,68,67,66,65,64,63,54};
// X2 local bits: r = g - 7.
constexpr unsigned cX2M[21] = {
    0x004,0x008,0x010,0x020,0x040,0x080,
    0x606,0x60C,0x618,0x630,0x660,0x6C0,0x780,
    0x305,0x30A,0x314,0x328,0x350,0x3A0,0x240,0x180};
constexpr unsigned char cX2A[21] = {
    26,25,24,23,22,21,
    44,43,42,41,40,39,38,
    62,61,60,59,58,57,56,55};

constexpr int ctzc(unsigned x) { int n = 0; while (!(x & 1u)) { x >>= 1; ++n; } return n; }

// apply one gate (pairing coordinate C in orbit space) to 8-elem register set
template<int C>
__device__ __forceinline__ void applyG(float2* E, float2 g) {
    constexpr int L = C & (-C);
#pragma unroll
    for (int v = 0; v < 8; ++v)
        if (!(v & L)) bfly(E[v], E[v ^ C], g.x, g.y);
}

// three commuting gates per round over an 8-element orbit; all compile-time.
template<unsigned M1, unsigned M2, unsigned M3, int T, int NT>
__device__ __forceinline__ void triR(float2* t, float2 g1, float2 g2, float2 g3) {
    constexpr unsigned z1 = M1 & (0u - M1);
    constexpr unsigned B2a = (M2 & z1) ? (M2 ^ M1) : M2;
    constexpr unsigned z2 = B2a & (0u - B2a);
    constexpr unsigned B1a = (M1 & z2) ? (M1 ^ B2a) : M1;
    constexpr unsigned B3a = (M3 & z1) ? (M3 ^ B1a) : M3;
    constexpr unsigned B3b = (B3a & z2) ? (B3a ^ B2a) : B3a;
    constexpr unsigned z3 = B3b & (0u - B3b);
    constexpr unsigned B1 = (B1a & z3) ? (B1a ^ B3b) : B1a;
    constexpr unsigned B2 = (B2a & z3) ? (B2a ^ B3b) : B2a;
    constexpr unsigned B3 = B3b;
    constexpr int c1 = ((M1 & z1) ? 1 : 0) | ((M1 & z2) ? 2 : 0) | ((M1 & z3) ? 4 : 0);
    constexpr int c2 = ((M2 & z1) ? 1 : 0) | ((M2 & z2) ? 2 : 0) | ((M2 & z3) ? 4 : 0);
    constexpr int c3 = ((M3 & z1) ? 1 : 0) | ((M3 & z2) ? 2 : 0) | ((M3 & z3) ? 4 : 0);
    constexpr int q1 = ctzc(z1), q2 = ctzc(z2), q3 = ctzc(z3);
    constexpr int pa = (q1 < q2 ? (q1 < q3 ? q1 : q3) : (q2 < q3 ? q2 : q3));
    constexpr int pc = (q1 > q2 ? (q1 > q3 ? q1 : q3) : (q2 > q3 ? q2 : q3));
    constexpr int pb = q1 + q2 + q3 - pa - pc;
#pragma unroll
    for (int it = 0; it < (T / 8) / NT; ++it) {
        unsigned k = (unsigned)threadIdx.x + (unsigned)(it * NT);
        unsigned i = ((k >> pa) << (pa + 1)) | (k & ((1u << pa) - 1u));
        i = ((i >> pb) << (pb + 1)) | (i & ((1u << pb) - 1u));
        i = ((i >> pc) << (pc + 1)) | (i & ((1u << pc) - 1u));
        int idx[8];
        float2 E[8];
#pragma unroll
        for (int v = 0; v < 8; ++v) {
            unsigned e = i ^ ((v & 1) ? B1 : 0u) ^ ((v & 2) ? B2 : 0u) ^ ((v & 4) ? B3 : 0u);
            idx[v] = PAD16((int)e);
            E[v] = t[idx[v]];
        }
        applyG<c1>(E, g1);
        applyG<c2>(E, g2);
        applyG<c3>(E, g3);
#pragma unroll
        for (int v = 0; v < 8; ++v) t[idx[v]] = E[v];
    }
}

// ---- X1: analytic init (Gray-orbit ratio walk) + 33 gates; 64 x 512 -------
__global__ __launch_bounds__(512) void kX1(float2* __restrict__ out, const float* __restrict__ qw) {
    __shared__ float2 t[4352];
    __shared__ float2 g[33];
    int tid = threadIdx.x;
    if (tid < 33) { float th = qw[cX1A[tid]] * 0.5f; g[tid] = make_float2(cosf(th), sinf(th)); }
    float c0[NW], s0[NW];
#pragma unroll
    for (int w = 0; w < NW; ++w) { float th = qw[w] * 0.5f; c0[w] = cosf(th); s0[w] = sinf(th); }
    unsigned blk = blockIdx.x;                 // global bits 9..14
    unsigned l0 = 8u * (unsigned)tid;
    unsigned b0 = (l0 & 511u) | (blk << 9) | ((l0 >> 9) << 15);
    unsigned i0 = pinv18(b0);
    float m0 = 1.f;
#pragma unroll
    for (int p = 0; p < 18; ++p) m0 *= ((i0 >> p) & 1u) ? s0[17 - p] : c0[17 - p];
    float rA0 = s0[17] / c0[17], rB0 = c0[17] / s0[17];
    float rA1 = s0[16] / c0[16], rB1 = c0[16] / s0[16];
    float rA2 = s0[15] / c0[15], rB2 = c0[15] / s0[15];
    float rA16 = s0[1] / c0[1], rB16 = c0[1] / s0[1];
    float rA17 = s0[0] / c0[0], rB17 = c0[0] / s0[0];
    float2 E[8];
    {
        unsigned i = i0;
        float m = m0;
        auto quad = [&](unsigned ii, float mm) {
            int k4 = __popc(ii) & 3;
            if      (k4 == 0) return make_float2( mm, 0.f);
            else if (k4 == 1) return make_float2(0.f, -mm);
            else if (k4 == 2) return make_float2(-mm, 0.f);
            else              return make_float2(0.f,  mm);
        };
        auto togQ1 = [&]() {    // bits {0,16,17}
            i ^= 0x30001u;
            m *= ((i) & 1u) ? rA0 : rB0;
            m *= ((i >> 16) & 1u) ? rA16 : rB16;
            m *= ((i >> 17) & 1u) ? rA17 : rB17;
        };
        auto togQ2 = [&]() {    // bits {0,1}
            i ^= 0x3u;
            m *= ((i) & 1u) ? rA0 : rB0;
            m *= ((i >> 1) & 1u) ? rA1 : rB1;
        };
        auto togQ4 = [&]() {    // bits {1,2}
            i ^= 0x6u;
            m *= ((i >> 1) & 1u) ? rA1 : rB1;
            m *= ((i >> 2) & 1u) ? rA2 : rB2;
        };
        E[0] = quad(i, m);
        togQ1(); E[1] = quad(i, m);
        togQ2(); E[3] = quad(i, m);
        togQ1(); E[2] = quad(i, m);
        togQ4(); E[6] = quad(i, m);
        togQ1(); E[7] = quad(i, m);
        togQ2(); E[5] = quad(i, m);
        togQ1(); E[4] = quad(i, m);
    }
    __syncthreads();                           // g ready
    applyG<1>(E, g[0]);
    applyG<2>(E, g[1]);
    applyG<4>(E, g[2]);
#pragma unroll
    for (int v = 0; v < 8; ++v) t[PAD16(8 * tid + v)] = E[v];
    __syncthreads();
#define TX1(a) triR<cX1M[a], cX1M[(a)+1], cX1M[(a)+2], 4096, 512>(t, g[a], g[(a)+1], g[(a)+2]); __syncthreads();
    TX1(3) TX1(6) TX1(9) TX1(12) TX1(15) TX1(18) TX1(21) TX1(24) TX1(27) TX1(30)
#undef TX1
#pragma unroll
    for (int r = 0; r < 8; ++r) {
        int l = tid + 512 * r;
        unsigned b = ((unsigned)l & 511u) | (blk << 9) | (((unsigned)l >> 9) << 15);
        out[b] = t[PAD16(l)];
    }
}

// ---- X2: 21 gates on span {7..17} + bf16 |amp|^2 + P^3 scatter; 128 x 256 --
__global__ __launch_bounds__(256) void kX2(const float2* __restrict__ in,
                                           unsigned short* __restrict__ probs,
                                           const float* __restrict__ qw) {
    __shared__ float2 t[2176];
    __shared__ float2 g[21];
    int tid = threadIdx.x;
    if (tid < 21) { float th = qw[cX2A[tid]] * 0.5f; g[tid] = make_float2(cosf(th), sinf(th)); }
    unsigned blk = blockIdx.x;                 // global bits 0..6
#pragma unroll
    for (int r = 0; r < 8; ++r) {
        int l = tid + 256 * r;
        t[PAD16(l)] = in[blk | ((unsigned)l << 7)];
    }
    __syncthreads();
#define TX2(a) triR<cX2M[a], cX2M[(a)+1], cX2M[(a)+2], 2048, 256>(t, g[a], g[(a)+1], g[(a)+2]); __syncthreads();
    TX2(0) TX2(3) TX2(6) TX2(9) TX2(12) TX2(15) TX2(18)
#undef TX2
#pragma unroll
    for (int r = 0; r < 8; ++r) {
        int l = tid + 256 * r;
        unsigned b = blk | ((unsigned)l << 7);
        unsigned pb = perm18(perm18(perm18(b)));
        float2 a = t[PAD16(l)];
        probs[pb] = (unsigned short)f2bf(a.x * a.x + a.y * a.y);
    }
}

// ---- k_mm: MFMA logits partials; bf16 p0; 512 blocks x 4 chunks ------------
__global__ __launch_bounds__(256) void k_mm(const unsigned short* __restrict__ p0,
                                            const float* __restrict__ W,
                                            float* __restrict__ partial) {
    __shared__ short Wl[64][136];
    __shared__ short Pl[16][136];
    __shared__ unsigned Tsh[16];
    int tid = threadIdx.x;
    if (tid < 16) {
        unsigned v = (unsigned)tid;
#pragma unroll
        for (int r = 0; r < 4; ++r) v = perm18(v);
        Tsh[tid] = v;
    }
    __syncthreads();

    unsigned d00 = (unsigned)blockIdx.x * (CH * CPB);
    int wrow = tid >> 5;
    int wcol = (tid & 31) * 4;
    int prow = tid >> 7;
    int pcol = tid & 127;
    unsigned Tp[8];
#pragma unroll
    for (int t = 0; t < 8; ++t) Tp[t] = Tsh[prow + 2 * t];

    int lane = tid & 63, wv = tid >> 6;
    int arow = lane & 15, kg = (lane >> 4) * 8;
    f32x4 acc = {0.f, 0.f, 0.f, 0.f};
    float4 wr[8];
    unsigned short pr[8];

#pragma unroll
    for (int t = 0; t < 8; ++t)
        wr[t] = *(const float4*)&W[(size_t)(wrow + 8 * t) * DIM + d00 + wcol];
#pragma unroll
    for (int t = 0; t < 8; ++t)
        pr[t] = p0[(d00 ^ (Tp[t] & ~127u)) + pcol];
#pragma unroll
    for (int t = 0; t < 8; ++t) {
        short4 b = make_short4(f2bf(wr[t].x), f2bf(wr[t].y), f2bf(wr[t].z), f2bf(wr[t].w));
        *(short4*)&Wl[wrow + 8 * t][wcol] = b;
    }
#pragma unroll
    for (int t = 0; t < 8; ++t)
        Pl[prow + 2 * t][pcol ^ (Tp[t] & 127u)] = (short)pr[t];
    __syncthreads();

    for (int cc = 0; cc < CPB; ++cc) {
        if (cc + 1 < CPB) {
            unsigned d1 = d00 + (unsigned)(cc + 1) * CH;
#pragma unroll
            for (int t = 0; t < 8; ++t)
                wr[t] = *(const float4*)&W[(size_t)(wrow + 8 * t) * DIM + d1 + wcol];
#pragma unroll
            for (int t = 0; t < 8; ++t)
                pr[t] = p0[(d1 ^ (Tp[t] & ~127u)) + pcol];
        }
#pragma unroll
        for (int kk = 0; kk < 4; ++kk) {
            short8 a = *(const short8*)&Pl[arow][kk * 32 + kg];
            short8 b = *(const short8*)&Wl[16 * wv + arow][kk * 32 + kg];
            acc = __builtin_amdgcn_mfma_f32_16x16x32_bf16(a, b, acc, 0, 0, 0);
        }
        __syncthreads();
        if (cc + 1 < CPB) {
#pragma unroll
            for (int t = 0; t < 8; ++t) {
                short4 b = make_short4(f2bf(wr[t].x), f2bf(wr[t].y), f2bf(wr[t].z), f2bf(wr[t].w));
                *(short4*)&Wl[wrow + 8 * t][wcol] = b;
            }
#pragma unroll
            for (int t = 0; t < 8; ++t)
                Pl[prow + 2 * t][pcol ^ (Tp[t] & 127u)] = (short)pr[t];
            __syncthreads();
        }
    }

    float* dst = partial + (size_t)blockIdx.x * 1024;
#pragma unroll
    for (int r = 0; r < 4; ++r) {
        int jrow = (lane >> 4) * 4 + r;
        dst[jrow * 64 + 16 * wv + (lane & 15)] = acc[r];
    }
}

// ---- finalize: reduce partials -> logits; lookup + sigmoid -----------------
__global__ __launch_bounds__(256) void k_finalize(const float* __restrict__ partial,
                                                  const float* __restrict__ bias,
                                                  const int* __restrict__ x,
                                                  float* __restrict__ out) {
    int b = blockIdx.x;
    int tid = threadIdx.x;
    int ji = tid & 15, ci = tid >> 4;
    int jo = b * 16 + ji;
    float sum = 0.f;
#pragma unroll 8
    for (int c = ci; c < NMM; c += 16)
        sum += partial[(size_t)c * 1024 + jo];
    __shared__ float red[16][17];
    __shared__ float lg[16];
    __shared__ int sidx[32];
    red[ci][ji] = sum;
    if (tid < 32) {
        const int* xb = x + (size_t)tid * (16384 * 4);
        sidx[tid] = 8 * xb[0] + 4 * xb[1] + 2 * xb[2] + xb[3];
    }
    __syncthreads();
    if (ci == 0) {
        float s = 0.f;
#pragma unroll
        for (int k = 0; k < 16; ++k) s += red[k][ji];
        lg[ji] = s + bias[jo & 63];
    }
    __syncthreads();
    int myidx = b >> 2, o0 = (b & 3) * 16;
#pragma unroll
    for (int r = 0; r < 2; ++r) {
        int slot = tid + 256 * r;
        int bb = slot >> 4, k = slot & 15;
        if (sidx[bb] == myidx) {
            float z = lg[k];
            out[bb * 64 + o0 + k] = 1.f / (1.f + expf(-z));
        }
    }
}

extern "C" void kernel_launch(void* const* d_in, const int* in_sizes, int n_in,
                              void* d_out, int out_size, void* d_ws, size_t ws_size,
                              hipStream_t stream) {
    const int*   x    = (const int*)d_in[0];
    const float* qw   = (const float*)d_in[1];
    const float* W    = (const float*)d_in[2];
    const float* bias = (const float*)d_in[3];
    float* out = (float*)d_out;

    char* ws = (char*)d_ws;
    float2*         buf0    = (float2*)(ws + (1ull << 20));         // 2 MB
    unsigned short* probs   = (unsigned short*)(ws + (8ull << 20)); // 0.5 MB
    float*          partial = (float*)(ws + (16ull << 20));         // 2 MB

    kX1<<<64, 512, 0, stream>>>(buf0, qw);
    kX2<<<128, 256, 0, stream>>>(buf0, probs, qw);
    k_mm<<<NMM, 256, 0, stream>>>(probs, W, partial);
    k_finalize<<<64, 256, 0, stream>>>(partial, bias, x, out);
}